// Round 16
// baseline (165.625 us; speedup 1.0000x reference)
//
#include <hip/hip_runtime.h>
#include <math.h>

// Problem constants
#define NRAYS        32768
#define MARCH_ITERS  64
#define EPS_         1e-4f
#define STEP_        ((1.0f + 1.0f/64.0f) / 64.0f)   // exact in fp32

typedef __attribute__((ext_vector_type(8)))  short    short8;   // 8 bf16
typedef __attribute__((ext_vector_type(4)))  float    float4v;  // C/D frag
typedef __attribute__((ext_vector_type(2)))  float    float2v;  // pk-f32 pair
typedef __attribute__((ext_vector_type(4)))  unsigned uint4v;
typedef __attribute__((ext_vector_type(2)))  unsigned uint2v;

__device__ __forceinline__ short8 mk_frag(unsigned p0, unsigned p1,
                                          unsigned p2, unsigned p3) {
    uint4v v = {p0, p1, p2, p3};
    return __builtin_bit_cast(short8, v);
}

// One v_perm_b32: low16 = trunc-bf16(a), high16 = trunc-bf16(b).
__device__ __forceinline__ unsigned packbf(unsigned a, unsigned b) {
    return __builtin_amdgcn_perm(b, a, 0x07060302u);
}

// 2-way split: hi + residual (packbf of r truncates -> the mid limb).
struct Split2 { unsigned h, r; };
__device__ __forceinline__ Split2 split2(float x) {
    unsigned xu = __float_as_uint(x);
    float xh = __uint_as_float(xu & 0xFFFF0000u);
    float rr = x - xh;                        // exact residual
    return { xu, __float_as_uint(rr) };
}

// packed f32 fma -> v_pk_fma_f32 (lane-exact == 2 scalar v_fma_f32)
__device__ __forceinline__ float2v fma2(float2v a, float2v b, float2v c) {
    return __builtin_elementwise_fma(a, b, c);
}

// Butterflies via permlane-swap builtins (R26-verified: PASS, bit-identical
// to shfl_xor by fp-add commutativity). Fallback = R24's verified DS forms.
__device__ __forceinline__ float xor16_sum(float x) {
#if __has_builtin(__builtin_amdgcn_permlane16_swap)
    unsigned u = __float_as_uint(x);
    uint2v r = __builtin_amdgcn_permlane16_swap(u, u, false, false);
    return __uint_as_float(r.x) + __uint_as_float(r.y);
#else
    float p = __int_as_float(
        __builtin_amdgcn_ds_swizzle(__float_as_int(x), 0x401F));
    return x + p;
#endif
}
__device__ __forceinline__ float xor32_sum(float x) {
#if __has_builtin(__builtin_amdgcn_permlane32_swap)
    unsigned u = __float_as_uint(x);
    uint2v r = __builtin_amdgcn_permlane32_swap(u, u, false, false);
    return __uint_as_float(r.x) + __uint_as_float(r.y);
#else
    return x + __shfl_xor(x, 32, 64);
#endif
}

// R31: R27 base (verified best: 107.7us; unroll 2 -- R30 showed unroll 4
// regresses) + T5 s_setprio around the contiguous 40-MFMA cluster.
// Theory: the residual ~40% per-SIMD idle survives all dataflow levers
// (occupancy R18/20/28, inst count R21, fusion R22, pipelining R24/27/
// 30, MFMA chains R25, DS removal R26). Remaining candidate: the two
// co-resident waves run IDENTICAL streams and phase-align -- both in
// the MFMA-feed phase (VALU port gaps), then both in the serial VALU
// phase (matrix pipe gaps). s_setprio(1) on the MFMA cluster biases CU
// arbitration toward the MFMA-issuing wave, keeping the matrix pipe fed
// while the other wave runs its VALU phase (guide T5: +4-7% on attn,
// whose structure -- per-wave serial chain + MFMA cluster, no barriers
// -- matches ours; null only on barrier-lockstep GEMM, and we have no
// barriers). Pure scheduling hint: arithmetic bit-identical to R27 ->
// absmax must stay exactly 0.00390625.
// 2048 single-wave blocks, 16 rays each, march+tput fused per wave.
// Zero LDS; zero DS in the loop; waves_per_eu(2,8).
// MFMA layouts (R6-verified): A[row=lane&15][k=quad*8+j],
// B[k=quad*8+j][col=lane&15], C/D col=lane&15 row=quad*4+reg.
// Precision: march L2 = 3 products (m,h)(h,m)(h,h); tput L2 = 2 products.
// march 3rd limb product is load-bearing (dropping it -> d-error ~4e-3
// >> EPS=1e-4 -> mass hit-flips). Matrix work irreducible at 41.6us.
__global__ __launch_bounds__(64)
__attribute__((amdgpu_waves_per_eu(2, 8)))
void sdf_w19_k(
    const float* __restrict__ rays,
    const float* __restrict__ W0,  const float* __restrict__ b0,
    const float* __restrict__ W1,  const float* __restrict__ b1,
    const float* __restrict__ W2,  const float* __restrict__ b2,
    const float* __restrict__ Wr0, const float* __restrict__ br0,
    const float* __restrict__ Wr1, const float* __restrict__ br1,
    float* __restrict__ out)
{
    const int lane = threadIdx.x;             // 0..63, one wave per block
    const int quad = lane >> 4;
    const int m    = lane & 15;
    const int rayBase = blockIdx.x * 16;

    // ---- per-lane ray (ray = rayBase + m, replicated over quads) ----
    const float* rp = rays + (rayBase + m) * 6;
    const float ox = rp[0], oy = rp[1], oz = rp[2];
    const float dx = rp[3], dy = rp[4], dz = rp[5];

    // ---- linear-L1 coefficients (R21): L1 pre-act = a + c*s ----
    float2v a2[4][2], s2[4][2];
    #pragma unroll
    for (int t = 0; t < 4; ++t)
        #pragma unroll
        for (int p = 0; p < 2; ++p) {
            float av[2], sv[2];
            #pragma unroll
            for (int e = 0; e < 2; ++e) {
                int j = 32 * (t >> 1) + 8 * quad + 4 * (t & 1) + (2 * p + e);
                float w0c = W0[j], w1c = W0[64 + j], w2c = W0[128 + j];
                av[e] = fmaf(ox, w0c, fmaf(oy, w1c, fmaf(oz, w2c, b0[j])));
                sv[e] = fmaf(dx, w0c, fmaf(dy, w1c, dz * w2c));
            }
            a2[t][p] = (float2v){av[0], av[1]};
            s2[t][p] = (float2v){sv[0], sv[1]};
        }

    // ---- b1 (first-product C-input) and W2 (L3), rows j2 = 16t+4q+r ----
    float4v b1v[4];
    float2v w2a[4], w2b[4];
    #pragma unroll
    for (int t = 0; t < 4; ++t) {
        int base = 16 * t + 4 * quad;
        b1v[t] = (float4v){b1[base], b1[base + 1], b1[base + 2], b1[base + 3]};
        w2a[t] = (float2v){W2[base], W2[base + 1]};
        w2b[t] = (float2v){W2[base + 2], W2[base + 3]};
    }
    const float b2s = b2[0];

    // ---- W1 limbs: A2h (hi) + A2m (mid), 64 regs, shared by streams ----
    short8 A2h[2][4], A2m[2][4];
    #pragma unroll
    for (int h = 0; h < 2; ++h)
        #pragma unroll
        for (int t = 0; t < 4; ++t) {
            unsigned pm[4], ph[4];
            #pragma unroll
            for (int jp = 0; jp < 4; ++jp) {
                int k0 = 32 * h + quad * 8 + 2 * jp;
                int j2 = 16 * t + m;
                Split2 a = split2(W1[k0 * 64 + j2]);
                Split2 b = split2(W1[(k0 + 1) * 64 + j2]);
                pm[jp] = packbf(a.r, b.r);   // trunc(residual) == mid limb
                ph[jp] = packbf(a.h, b.h);   // trunc(full) == hi limb
            }
            A2m[h][t] = mk_frag(pm[0], pm[1], pm[2], pm[3]);
            A2h[h][t] = mk_frag(ph[0], ph[1], ph[2], ph[3]);
        }

    // ---- shared front-end: c -> L1 = relu(a + c*s) -> split2 pack ----
    const float2v z2 = {0.f, 0.f};
    auto front = [&](float cv, short8* BH, short8* BM) {
        const float2v c2 = {cv, cv};
        unsigned PH[4][2], PM[4][2];
        #pragma unroll
        for (int t = 0; t < 4; ++t) {
            float2v v01 = fma2(c2, s2[t][0], a2[t][0]);
            float2v v23 = fma2(c2, s2[t][1], a2[t][1]);
            v01 = __builtin_elementwise_max(v01, z2);
            v23 = __builtin_elementwise_max(v23, z2);
            unsigned u0 = __float_as_uint(v01.x), u1 = __float_as_uint(v01.y);
            unsigned u2 = __float_as_uint(v23.x), u3 = __float_as_uint(v23.y);
            PH[t][0] = packbf(u0, u1); PH[t][1] = packbf(u2, u3);
            float2v h01 = {__uint_as_float(u0 & 0xFFFF0000u),
                           __uint_as_float(u1 & 0xFFFF0000u)};
            float2v h23 = {__uint_as_float(u2 & 0xFFFF0000u),
                           __uint_as_float(u3 & 0xFFFF0000u)};
            float2v r01 = v01 - h01;   // pk sub, exact residual
            float2v r23 = v23 - h23;
            PM[t][0] = packbf(__float_as_uint(r01.x), __float_as_uint(r01.y));
            PM[t][1] = packbf(__float_as_uint(r23.x), __float_as_uint(r23.y));
        }
        #pragma unroll
        for (int h = 0; h < 2; ++h) {
            BH[h] = mk_frag(PH[2 * h][0], PH[2 * h][1],
                            PH[2 * h + 1][0], PH[2 * h + 1][1]);
            BM[h] = mk_frag(PM[2 * h][0], PM[2 * h][1],
                            PM[2 * h + 1][0], PM[2 * h + 1][1]);
        }
    };

    // ---- L3: in-lane relu*W2 (pk fma), permlane butterflies (no DS) ----
    auto l3 = [&](const float4v* C2) -> float {
        float2v q01 = {0.f, 0.f}, q23 = {0.f, 0.f};
        #pragma unroll
        for (int t = 0; t < 4; ++t) {
            float2v rel01 = __builtin_elementwise_max(
                (float2v){C2[t][0], C2[t][1]}, z2);
            float2v rel23 = __builtin_elementwise_max(
                (float2v){C2[t][2], C2[t][3]}, z2);
            q01 = fma2(rel01, w2a[t], q01);
            q23 = fma2(rel23, w2b[t], q23);
        }
        float part = (q01.x + q01.y) + (q23.x + q23.y);
        part = xor16_sum(part);                // == part + shfl_xor(part,16)
        part = xor32_sum(part);                // == part + shfl_xor(part,32)
        return b2s + part;
    };

    // tput L2: 2 products (h,m)(h,h), b1 folded into first. R22 chained.
    auto tputC2 = [&](const short8* BHt, const short8* BMt, float4v* C2t) {
        #pragma unroll
        for (int t = 0; t < 4; ++t)
            C2t[t] = __builtin_amdgcn_mfma_f32_16x16x32_bf16(
                A2h[0][t], BMt[0], b1v[t], 0, 0, 0);
        #pragma unroll
        for (int t = 0; t < 4; ++t)
            C2t[t] = __builtin_amdgcn_mfma_f32_16x16x32_bf16(
                A2h[1][t], BMt[1], C2t[t], 0, 0, 0);
        #pragma unroll
        for (int h = 0; h < 2; ++h)
            #pragma unroll
            for (int t = 0; t < 4; ++t)
                C2t[t] = __builtin_amdgcn_mfma_f32_16x16x32_bf16(
                    A2h[h][t], BHt[h], C2t[t], 0, 0, 0);
    };

    bool  hit = false;
    float cd  = 0.f;
    float cm  = 3.4e38f;

    // =========== FUSED loop: FIXED 64 iters, branch-free body ============
    // No early exit (R27): updates are predicated (hit latches, cd
    // frozen), post-all-hit iterations are exact no-ops -- matching the
    // reference scan's fixed trip count. unroll 2 (verified optimum).
    #pragma unroll 2
    for (int i = 0; i < MARCH_ITERS; ++i) {
        // 1) tput front (independent filler for the march backedge chain)
        float ti = STEP_ * (float)i;
        short8 BHt[2], BMt[2];
        front(ti, BHt, BMt);
        // 2) march front (needs cd)
        short8 BHm[2], BMm[2];
        front(cd, BHm, BMm);
        // 3) the 40-MFMA cluster at raised priority (T5): keeps the
        //    matrix pipe fed while the co-resident wave is in its VALU
        //    phase. march MFMAs first, tput MFMAs behind them.
        __builtin_amdgcn_s_setprio(1);
        float4v C2m[4], C2t[4];
        #pragma unroll
        for (int t = 0; t < 4; ++t)
            C2m[t] = __builtin_amdgcn_mfma_f32_16x16x32_bf16(
                A2m[0][t], BHm[0], b1v[t], 0, 0, 0);
        #pragma unroll
        for (int t = 0; t < 4; ++t)
            C2m[t] = __builtin_amdgcn_mfma_f32_16x16x32_bf16(
                A2m[1][t], BHm[1], C2m[t], 0, 0, 0);
        #pragma unroll
        for (int h = 0; h < 2; ++h)
            #pragma unroll
            for (int t = 0; t < 4; ++t)
                C2m[t] = __builtin_amdgcn_mfma_f32_16x16x32_bf16(
                    A2h[h][t], BMm[h], C2m[t], 0, 0, 0);
        #pragma unroll
        for (int h = 0; h < 2; ++h)
            #pragma unroll
            for (int t = 0; t < 4; ++t)
                C2m[t] = __builtin_amdgcn_mfma_f32_16x16x32_bf16(
                    A2h[h][t], BHm[h], C2m[t], 0, 0, 0);
        tputC2(BHt, BMt, C2t);
        __builtin_amdgcn_s_setprio(0);
        // 4) march finish (serial chain; tput MFMAs drain underneath)
        float dm = l3(C2m);
        bool c = (dm < EPS_) && (cd >= 0.f) && (cd <= 1.f);
        hit = hit || c;
        if (!hit) cd += dm;                    // predicated: v_cndmask
        // 5) tput finish
        cm = fminf(cm, l3(C2t));
    }

    // =========== trailing tput eval i = 64 ===============================
    {
        short8 BHt[2], BMt[2];
        front(STEP_ * 64.0f, BHt, BMt);
        float4v C2t[4];
        tputC2(BHt, BMt, C2t);
        cm = fminf(cm, l3(C2t));
    }

    // ---- reflection net: quad q handles hidden j in [16q, 16q+16) ----
    const float px = fmaf(dx, cd, ox), py = fmaf(dy, cd, oy), pz = fmaf(dz, cd, oz);
    float r0 = 0.f, r1 = 0.f, r2 = 0.f;
    #pragma unroll 4
    for (int jj = 0; jj < 16; ++jj) {
        int j = quad * 16 + jj;
        float a = fmaf(px, Wr0[j],
                  fmaf(py, Wr0[64 + j],
                  fmaf(pz, Wr0[128 + j],
                  fmaf(dx, Wr0[192 + j],
                  fmaf(dy, Wr0[256 + j],
                  fmaf(dz, Wr0[320 + j], br0[j]))))));
        a = fmaxf(a, 0.f);
        r0 = fmaf(a, Wr1[j * 3 + 0], r0);
        r1 = fmaf(a, Wr1[j * 3 + 1], r1);
        r2 = fmaf(a, Wr1[j * 3 + 2], r2);
    }
    r0 = xor16_sum(r0); r0 = xor32_sum(r0);
    r1 = xor16_sum(r1); r1 = xor32_sum(r1);
    r2 = xor16_sum(r2); r2 = xor32_sum(r2);
    r0 = 1.f / (1.f + expf(-(r0 + br1[0])));
    r1 = 1.f / (1.f + expf(-(r1 + br1[1])));
    r2 = 1.f / (1.f + expf(-(r2 + br1[2])));
    if (!hit) { r0 = 0.f; r1 = 0.f; r2 = 0.f; }
    if (lane < 16) {
        // one coalesced float4 store: rgb + tput
        float4v o4 = {r0, r1, r2, cm};
        *reinterpret_cast<float4v*>(out + (rayBase + lane) * 4) = o4;
    }
}

extern "C" void kernel_launch(void* const* d_in, const int* in_sizes, int n_in,
                              void* d_out, int out_size, void* d_ws, size_t ws_size,
                              hipStream_t stream) {
    const float* rays = (const float*)d_in[0];
    const float* W0   = (const float*)d_in[1];
    const float* b0   = (const float*)d_in[2];
    const float* W1   = (const float*)d_in[3];
    const float* b1   = (const float*)d_in[4];
    const float* W2   = (const float*)d_in[5];
    const float* b2   = (const float*)d_in[6];
    const float* Wr0  = (const float*)d_in[7];
    const float* br0  = (const float*)d_in[8];
    const float* Wr1  = (const float*)d_in[9];
    const float* br1  = (const float*)d_in[10];
    float* out = (float*)d_out;

    // 2048 single-wave blocks, 16 rays each, march+tput fused per wave
    // (R27 base, unroll 2 -- the verified optimum). R31: s_setprio(1)
    // around the 40-MFMA cluster (T5) to bias CU arbitration toward the
    // MFMA-issuing wave. Zero LDS; zero DS in loop; waves_per_eu(2,8).
    hipLaunchKernelGGL(sdf_w19_k, dim3(NRAYS / 16), dim3(64), 0, stream,
                       rays, W0, b0, W1, b1, W2, b2, Wr0, br0, Wr1, br1, out);
}

// Round 17
// 162.995 us; speedup vs baseline: 1.0161x; 1.0161x over previous
//
#include <hip/hip_runtime.h>
#include <math.h>

// Problem constants
#define NRAYS        32768
#define MARCH_ITERS  64
#define EPS_         1e-4f
#define STEP_        ((1.0f + 1.0f/64.0f) / 64.0f)   // exact in fp32

typedef __attribute__((ext_vector_type(8)))  short    short8;   // 8 bf16
typedef __attribute__((ext_vector_type(4)))  float    float4v;  // C/D frag
typedef __attribute__((ext_vector_type(2)))  float    float2v;  // pk-f32 pair
typedef __attribute__((ext_vector_type(4)))  unsigned uint4v;
typedef __attribute__((ext_vector_type(2)))  unsigned uint2v;

__device__ __forceinline__ short8 mk_frag(unsigned p0, unsigned p1,
                                          unsigned p2, unsigned p3) {
    uint4v v = {p0, p1, p2, p3};
    return __builtin_bit_cast(short8, v);
}

// One v_perm_b32: low16 = trunc-bf16(a), high16 = trunc-bf16(b).
__device__ __forceinline__ unsigned packbf(unsigned a, unsigned b) {
    return __builtin_amdgcn_perm(b, a, 0x07060302u);
}

// 2-way split: hi + residual (packbf of r truncates -> the mid limb).
struct Split2 { unsigned h, r; };
__device__ __forceinline__ Split2 split2(float x) {
    unsigned xu = __float_as_uint(x);
    float xh = __uint_as_float(xu & 0xFFFF0000u);
    float rr = x - xh;                        // exact residual
    return { xu, __float_as_uint(rr) };
}

// packed f32 fma -> v_pk_fma_f32 (lane-exact == 2 scalar v_fma_f32)
__device__ __forceinline__ float2v fma2(float2v a, float2v b, float2v c) {
    return __builtin_elementwise_fma(a, b, c);
}

// Butterflies via permlane-swap builtins (R26-verified: PASS, bit-identical
// to shfl_xor by fp-add commutativity). Fallback = R24's verified DS forms.
__device__ __forceinline__ float xor16_sum(float x) {
#if __has_builtin(__builtin_amdgcn_permlane16_swap)
    unsigned u = __float_as_uint(x);
    uint2v r = __builtin_amdgcn_permlane16_swap(u, u, false, false);
    return __uint_as_float(r.x) + __uint_as_float(r.y);
#else
    float p = __int_as_float(
        __builtin_amdgcn_ds_swizzle(__float_as_int(x), 0x401F));
    return x + p;
#endif
}
__device__ __forceinline__ float xor32_sum(float x) {
#if __has_builtin(__builtin_amdgcn_permlane32_swap)
    unsigned u = __float_as_uint(x);
    uint2v r = __builtin_amdgcn_permlane32_swap(u, u, false, false);
    return __uint_as_float(r.x) + __uint_as_float(r.y);
#else
    return x + __shfl_xor(x, 32, 64);
#endif
}

// R32 = R27 verbatim (verified session best: 107.7us rocprof / 163.8us
// harness). R30 (unroll 4) and R31 (s_setprio on the MFMA cluster) each
// measured 110.3 -- both reverted.
// Closed theory ledger (9 hypotheses probed across R16-R31): the two
// real levers were stream FUSION (R22, +12%: tput's 65 independent
// evals fill the march chain's in-order stall slots) and BREAK REMOVAL
// + unroll 2 (R27, +4%: the per-iter `if(__all(hit)) break` was a
// scheduling barrier; fixed-64 trip count matches the reference scan
// and post-all-hit iterations are exact no-ops since hit latches and
// cd freezes). Permlane butterflies (R26, +2%) removed all DS from the
// loop. Nulls: spill-fix alone (R18), residency/occupancy (R19/R20/
// R28), 19% inst cut (R21), manual pipelining (R24), MFMA chain-split
// (R25), unroll 4 (R30), setprio (R31).
// Structural constraint at conclusion: per-wave per-iter span ~4040 cyc
// vs ~1200 cyc pipe work; the residual is distributed in-order
// dependency stall on the 64x-serial march chain, with the only
// available independent stream already fused in. Floors: matrix pipe
// 41.6us (work-conserved); 3-limb march L2 is precision-load-bearing
// (2-limb -> d-error ~4e-3 >> EPS=1e-4). Further gains require fewer
// serial iterations (semantics), lower precision (fails threshold), or
// >2 streams/wave (register-impossible: R28 regressed at 1 wave/SIMD).
// 2048 single-wave blocks, 16 rays each, march+tput fused per wave.
// Zero LDS; zero DS in the loop; waves_per_eu(2,8).
// MFMA layouts (R6-verified): A[row=lane&15][k=quad*8+j],
// B[k=quad*8+j][col=lane&15], C/D col=lane&15 row=quad*4+reg.
// Precision: march L2 = 3 products (m,h)(h,m)(h,h); tput L2 = 2 products.
__global__ __launch_bounds__(64)
__attribute__((amdgpu_waves_per_eu(2, 8)))
void sdf_w20_k(
    const float* __restrict__ rays,
    const float* __restrict__ W0,  const float* __restrict__ b0,
    const float* __restrict__ W1,  const float* __restrict__ b1,
    const float* __restrict__ W2,  const float* __restrict__ b2,
    const float* __restrict__ Wr0, const float* __restrict__ br0,
    const float* __restrict__ Wr1, const float* __restrict__ br1,
    float* __restrict__ out)
{
    const int lane = threadIdx.x;             // 0..63, one wave per block
    const int quad = lane >> 4;
    const int m    = lane & 15;
    const int rayBase = blockIdx.x * 16;

    // ---- per-lane ray (ray = rayBase + m, replicated over quads) ----
    const float* rp = rays + (rayBase + m) * 6;
    const float ox = rp[0], oy = rp[1], oz = rp[2];
    const float dx = rp[3], dy = rp[4], dz = rp[5];

    // ---- linear-L1 coefficients (R21): L1 pre-act = a + c*s ----
    float2v a2[4][2], s2[4][2];
    #pragma unroll
    for (int t = 0; t < 4; ++t)
        #pragma unroll
        for (int p = 0; p < 2; ++p) {
            float av[2], sv[2];
            #pragma unroll
            for (int e = 0; e < 2; ++e) {
                int j = 32 * (t >> 1) + 8 * quad + 4 * (t & 1) + (2 * p + e);
                float w0c = W0[j], w1c = W0[64 + j], w2c = W0[128 + j];
                av[e] = fmaf(ox, w0c, fmaf(oy, w1c, fmaf(oz, w2c, b0[j])));
                sv[e] = fmaf(dx, w0c, fmaf(dy, w1c, dz * w2c));
            }
            a2[t][p] = (float2v){av[0], av[1]};
            s2[t][p] = (float2v){sv[0], sv[1]};
        }

    // ---- b1 (first-product C-input) and W2 (L3), rows j2 = 16t+4q+r ----
    float4v b1v[4];
    float2v w2a[4], w2b[4];
    #pragma unroll
    for (int t = 0; t < 4; ++t) {
        int base = 16 * t + 4 * quad;
        b1v[t] = (float4v){b1[base], b1[base + 1], b1[base + 2], b1[base + 3]};
        w2a[t] = (float2v){W2[base], W2[base + 1]};
        w2b[t] = (float2v){W2[base + 2], W2[base + 3]};
    }
    const float b2s = b2[0];

    // ---- W1 limbs: A2h (hi) + A2m (mid), 64 regs, shared by streams ----
    short8 A2h[2][4], A2m[2][4];
    #pragma unroll
    for (int h = 0; h < 2; ++h)
        #pragma unroll
        for (int t = 0; t < 4; ++t) {
            unsigned pm[4], ph[4];
            #pragma unroll
            for (int jp = 0; jp < 4; ++jp) {
                int k0 = 32 * h + quad * 8 + 2 * jp;
                int j2 = 16 * t + m;
                Split2 a = split2(W1[k0 * 64 + j2]);
                Split2 b = split2(W1[(k0 + 1) * 64 + j2]);
                pm[jp] = packbf(a.r, b.r);   // trunc(residual) == mid limb
                ph[jp] = packbf(a.h, b.h);   // trunc(full) == hi limb
            }
            A2m[h][t] = mk_frag(pm[0], pm[1], pm[2], pm[3]);
            A2h[h][t] = mk_frag(ph[0], ph[1], ph[2], ph[3]);
        }

    // ---- shared front-end: c -> L1 = relu(a + c*s) -> split2 pack ----
    const float2v z2 = {0.f, 0.f};
    auto front = [&](float cv, short8* BH, short8* BM) {
        const float2v c2 = {cv, cv};
        unsigned PH[4][2], PM[4][2];
        #pragma unroll
        for (int t = 0; t < 4; ++t) {
            float2v v01 = fma2(c2, s2[t][0], a2[t][0]);
            float2v v23 = fma2(c2, s2[t][1], a2[t][1]);
            v01 = __builtin_elementwise_max(v01, z2);
            v23 = __builtin_elementwise_max(v23, z2);
            unsigned u0 = __float_as_uint(v01.x), u1 = __float_as_uint(v01.y);
            unsigned u2 = __float_as_uint(v23.x), u3 = __float_as_uint(v23.y);
            PH[t][0] = packbf(u0, u1); PH[t][1] = packbf(u2, u3);
            float2v h01 = {__uint_as_float(u0 & 0xFFFF0000u),
                           __uint_as_float(u1 & 0xFFFF0000u)};
            float2v h23 = {__uint_as_float(u2 & 0xFFFF0000u),
                           __uint_as_float(u3 & 0xFFFF0000u)};
            float2v r01 = v01 - h01;   // pk sub, exact residual
            float2v r23 = v23 - h23;
            PM[t][0] = packbf(__float_as_uint(r01.x), __float_as_uint(r01.y));
            PM[t][1] = packbf(__float_as_uint(r23.x), __float_as_uint(r23.y));
        }
        #pragma unroll
        for (int h = 0; h < 2; ++h) {
            BH[h] = mk_frag(PH[2 * h][0], PH[2 * h][1],
                            PH[2 * h + 1][0], PH[2 * h + 1][1]);
            BM[h] = mk_frag(PM[2 * h][0], PM[2 * h][1],
                            PM[2 * h + 1][0], PM[2 * h + 1][1]);
        }
    };

    // ---- L3: in-lane relu*W2 (pk fma), permlane butterflies (no DS) ----
    auto l3 = [&](const float4v* C2) -> float {
        float2v q01 = {0.f, 0.f}, q23 = {0.f, 0.f};
        #pragma unroll
        for (int t = 0; t < 4; ++t) {
            float2v rel01 = __builtin_elementwise_max(
                (float2v){C2[t][0], C2[t][1]}, z2);
            float2v rel23 = __builtin_elementwise_max(
                (float2v){C2[t][2], C2[t][3]}, z2);
            q01 = fma2(rel01, w2a[t], q01);
            q23 = fma2(rel23, w2b[t], q23);
        }
        float part = (q01.x + q01.y) + (q23.x + q23.y);
        part = xor16_sum(part);                // == part + shfl_xor(part,16)
        part = xor32_sum(part);                // == part + shfl_xor(part,32)
        return b2s + part;
    };

    // tput L2: 2 products (h,m)(h,h), b1 folded into first. R22 chained.
    auto tputC2 = [&](const short8* BHt, const short8* BMt, float4v* C2t) {
        #pragma unroll
        for (int t = 0; t < 4; ++t)
            C2t[t] = __builtin_amdgcn_mfma_f32_16x16x32_bf16(
                A2h[0][t], BMt[0], b1v[t], 0, 0, 0);
        #pragma unroll
        for (int t = 0; t < 4; ++t)
            C2t[t] = __builtin_amdgcn_mfma_f32_16x16x32_bf16(
                A2h[1][t], BMt[1], C2t[t], 0, 0, 0);
        #pragma unroll
        for (int h = 0; h < 2; ++h)
            #pragma unroll
            for (int t = 0; t < 4; ++t)
                C2t[t] = __builtin_amdgcn_mfma_f32_16x16x32_bf16(
                    A2h[h][t], BHt[h], C2t[t], 0, 0, 0);
    };

    bool  hit = false;
    float cd  = 0.f;
    float cm  = 3.4e38f;

    // =========== FUSED loop: FIXED 64 iters, branch-free body ============
    // No early exit (R27): updates are predicated (hit latches, cd
    // frozen), post-all-hit iterations are exact no-ops -- matching the
    // reference scan's fixed trip count. unroll 2: verified optimum
    // (1 -> 112, 2 -> 107.7, 4 -> 110.3).
    #pragma unroll 2
    for (int i = 0; i < MARCH_ITERS; ++i) {
        // 1) tput front (independent filler for the march backedge chain)
        float ti = STEP_ * (float)i;
        short8 BHt[2], BMt[2];
        front(ti, BHt, BMt);
        // 2) march front (needs cd)
        short8 BHm[2], BMm[2];
        front(cd, BHm, BMm);
        // 3) march MFMAs first, tput MFMAs behind them
        float4v C2m[4], C2t[4];
        #pragma unroll
        for (int t = 0; t < 4; ++t)
            C2m[t] = __builtin_amdgcn_mfma_f32_16x16x32_bf16(
                A2m[0][t], BHm[0], b1v[t], 0, 0, 0);
        #pragma unroll
        for (int t = 0; t < 4; ++t)
            C2m[t] = __builtin_amdgcn_mfma_f32_16x16x32_bf16(
                A2m[1][t], BHm[1], C2m[t], 0, 0, 0);
        #pragma unroll
        for (int h = 0; h < 2; ++h)
            #pragma unroll
            for (int t = 0; t < 4; ++t)
                C2m[t] = __builtin_amdgcn_mfma_f32_16x16x32_bf16(
                    A2h[h][t], BMm[h], C2m[t], 0, 0, 0);
        #pragma unroll
        for (int h = 0; h < 2; ++h)
            #pragma unroll
            for (int t = 0; t < 4; ++t)
                C2m[t] = __builtin_amdgcn_mfma_f32_16x16x32_bf16(
                    A2h[h][t], BHm[h], C2m[t], 0, 0, 0);
        tputC2(BHt, BMt, C2t);
        // 4) march finish (serial chain; tput MFMAs drain underneath)
        float dm = l3(C2m);
        bool c = (dm < EPS_) && (cd >= 0.f) && (cd <= 1.f);
        hit = hit || c;
        if (!hit) cd += dm;                    // predicated: v_cndmask
        // 5) tput finish
        cm = fminf(cm, l3(C2t));
    }

    // =========== trailing tput eval i = 64 ===============================
    {
        short8 BHt[2], BMt[2];
        front(STEP_ * 64.0f, BHt, BMt);
        float4v C2t[4];
        tputC2(BHt, BMt, C2t);
        cm = fminf(cm, l3(C2t));
    }

    // ---- reflection net: quad q handles hidden j in [16q, 16q+16) ----
    const float px = fmaf(dx, cd, ox), py = fmaf(dy, cd, oy), pz = fmaf(dz, cd, oz);
    float r0 = 0.f, r1 = 0.f, r2 = 0.f;
    #pragma unroll 4
    for (int jj = 0; jj < 16; ++jj) {
        int j = quad * 16 + jj;
        float a = fmaf(px, Wr0[j],
                  fmaf(py, Wr0[64 + j],
                  fmaf(pz, Wr0[128 + j],
                  fmaf(dx, Wr0[192 + j],
                  fmaf(dy, Wr0[256 + j],
                  fmaf(dz, Wr0[320 + j], br0[j]))))));
        a = fmaxf(a, 0.f);
        r0 = fmaf(a, Wr1[j * 3 + 0], r0);
        r1 = fmaf(a, Wr1[j * 3 + 1], r1);
        r2 = fmaf(a, Wr1[j * 3 + 2], r2);
    }
    r0 = xor16_sum(r0); r0 = xor32_sum(r0);
    r1 = xor16_sum(r1); r1 = xor32_sum(r1);
    r2 = xor16_sum(r2); r2 = xor32_sum(r2);
    r0 = 1.f / (1.f + expf(-(r0 + br1[0])));
    r1 = 1.f / (1.f + expf(-(r1 + br1[1])));
    r2 = 1.f / (1.f + expf(-(r2 + br1[2])));
    if (!hit) { r0 = 0.f; r1 = 0.f; r2 = 0.f; }
    if (lane < 16) {
        // one coalesced float4 store: rgb + tput
        float4v o4 = {r0, r1, r2, cm};
        *reinterpret_cast<float4v*>(out + (rayBase + lane) * 4) = o4;
    }
}

extern "C" void kernel_launch(void* const* d_in, const int* in_sizes, int n_in,
                              void* d_out, int out_size, void* d_ws, size_t ws_size,
                              hipStream_t stream) {
    const float* rays = (const float*)d_in[0];
    const float* W0   = (const float*)d_in[1];
    const float* b0   = (const float*)d_in[2];
    const float* W1   = (const float*)d_in[3];
    const float* b1   = (const float*)d_in[4];
    const float* W2   = (const float*)d_in[5];
    const float* b2   = (const float*)d_in[6];
    const float* Wr0  = (const float*)d_in[7];
    const float* br0  = (const float*)d_in[8];
    const float* Wr1  = (const float*)d_in[9];
    const float* br1  = (const float*)d_in[10];
    float* out = (float*)d_out;

    // 2048 single-wave blocks, 16 rays each, march+tput fused per wave.
    // R32 = R27 verbatim: the session's verified best configuration
    // (fixed-64 branch-free fused loop, unroll 2, permlane butterflies,
    // linear-L1, zero LDS/DS). R30/R31 add-ons reverted (each -2.4%).
    hipLaunchKernelGGL(sdf_w20_k, dim3(NRAYS / 16), dim3(64), 0, stream,
                       rays, W0, b0, W1, b1, W2, b2, Wr0, br0, Wr1, br1, out);
}